// Round 1
// baseline (119.448 us; speedup 1.0000x reference)
//
#include <hip/hip_runtime.h>
#include <float.h>
#include <math.h>

#define F_MAX 512
#define RED_BLOCKS 256

// ---------------------------------------------------------------------------
// Frame math: quaternion normalize, qmult with offset quat, t_all assembly,
// gather by opt_frames, tdiff/qdiff. F=240 -> single block.
// ---------------------------------------------------------------------------
__global__ __launch_bounds__(256) void frames_kernel(
    const float* __restrict__ tr,   // (1,1,F,3)
    const float* __restrict__ q,    // (1,F,4)
    const float* __restrict__ off,  // (1,1,F,7)
    const int*   __restrict__ of,   // (F,)
    float* __restrict__ out_t,      // (F,3)
    float* __restrict__ out_q,      // (F,4)
    float* __restrict__ out_td,     // (F,)
    float* __restrict__ out_qd,     // (F,)
    int F)
{
    __shared__ float qall[F_MAX][4];
    __shared__ float tall[F_MAX][3];
    const int tid = threadIdx.x;

    for (int f = tid; f < F; f += blockDim.x) {
        // qn = q / ||q||
        float w1 = q[4*f+0], x1 = q[4*f+1], y1 = q[4*f+2], z1 = q[4*f+3];
        float n1 = sqrtf(w1*w1 + x1*x1 + y1*y1 + z1*z1);
        w1 /= n1; x1 /= n1; y1 /= n1; z1 /= n1;
        // offn = offsets[...,3:7] / ||.||
        float w0 = off[7*f+3], x0 = off[7*f+4], y0 = off[7*f+5], z0 = off[7*f+6];
        float n0 = sqrtf(w0*w0 + x0*x0 + y0*y0 + z0*z0);
        w0 /= n0; x0 /= n0; y0 /= n0; z0 /= n0;
        // qprod = _qmult(qn, offn)
        float pw = -x1*x0 - y1*y0 - z1*z0 + w1*w0;
        float px =  x1*w0 + y1*z0 - z1*y0 + w1*x0;
        float py = -x1*z0 + y1*w0 + z1*x0 + w1*y0;
        float pz =  x1*y0 - y1*x0 + z1*w0 + w1*z0;
        if (f == 0) { pw = w1; px = x1; py = y1; pz = z1; }  // q_all[0] = qn[0]
        qall[f][0] = pw; qall[f][1] = px; qall[f][2] = py; qall[f][3] = pz;
        // t_all: frame 0 raw, frames >=1 add offsets[...,:3]
        float o0 = 0.f, o1 = 0.f, o2 = 0.f;
        if (f >= 1) { o0 = off[7*f+0]; o1 = off[7*f+1]; o2 = off[7*f+2]; }
        tall[f][0] = tr[3*f+0] + o0;
        tall[f][1] = tr[3*f+1] + o1;
        tall[f][2] = tr[3*f+2] + o2;
    }
    __syncthreads();

    for (int j = tid; j < F; j += blockDim.x) {
        const int fj = of[j];
        out_t[3*j+0] = tall[fj][0];
        out_t[3*j+1] = tall[fj][1];
        out_t[3*j+2] = tall[fj][2];
        out_q[4*j+0] = qall[fj][0];
        out_q[4*j+1] = qall[fj][1];
        out_q[4*j+2] = qall[fj][2];
        out_q[4*j+3] = qall[fj][3];

        float wj = (j == 0) ? 0.0f : (float)(of[j] - of[j-1]);

        // tdiff
        float td = 0.0f;
        if (j >= 1) {
            const int fp = of[j-1];
            float s = 0.0f;
            #pragma unroll
            for (int c = 0; c < 3; ++c) {
                float d = fabsf(tall[fj][c] - tall[fp][c]);
                if (d < 0.2f) d = 0.0f;
                s += d * d;
            }
            td = wj * sqrtf(s);
        }
        out_td[j] = td;

        // qdiff
        float qd;
        if (j == 0) {
            float s = qall[F-1][0]*qall[F-1][0] + qall[F-1][1]*qall[F-1][1]
                    + qall[F-1][2]*qall[F-1][2] + qall[F-1][3]*qall[F-1][3];
            qd = wj * (1.0f - s*s);   // wj == 0
        } else {
            int ia = fj - 1;
            if (ia < 0) ia += F;      // JAX negative-index wrap
            float s = qall[ia][0]*qall[fj][0] + qall[ia][1]*qall[fj][1]
                    + qall[ia][2]*qall[fj][2] + qall[ia][3]*qall[fj][3];
            qd = wj * (1.0f - s*s);
        }
        out_qd[j] = qd;
    }
}

// ---------------------------------------------------------------------------
// Per-component min/max over V vertices of (iv + vp); partials per block.
// ---------------------------------------------------------------------------
__global__ __launch_bounds__(256) void minmax_kernel(
    const float* __restrict__ iv, const float* __restrict__ vp, int V,
    float* __restrict__ partial)
{
    float mx0=-FLT_MAX, mx1=-FLT_MAX, mx2=-FLT_MAX;
    float mn0= FLT_MAX, mn1= FLT_MAX, mn2= FLT_MAX;
    for (int v = blockIdx.x * blockDim.x + threadIdx.x; v < V;
         v += gridDim.x * blockDim.x) {
        float a0 = iv[3*v+0] + vp[3*v+0];
        float a1 = iv[3*v+1] + vp[3*v+1];
        float a2 = iv[3*v+2] + vp[3*v+2];
        mx0 = fmaxf(mx0, a0); mn0 = fminf(mn0, a0);
        mx1 = fmaxf(mx1, a1); mn1 = fminf(mn1, a1);
        mx2 = fmaxf(mx2, a2); mn2 = fminf(mn2, a2);
    }
    __shared__ float s[256][6];
    const int t = threadIdx.x;
    s[t][0]=mx0; s[t][1]=mx1; s[t][2]=mx2; s[t][3]=mn0; s[t][4]=mn1; s[t][5]=mn2;
    __syncthreads();
    for (int w = 128; w >= 1; w >>= 1) {
        if (t < w) {
            s[t][0] = fmaxf(s[t][0], s[t+w][0]);
            s[t][1] = fmaxf(s[t][1], s[t+w][1]);
            s[t][2] = fmaxf(s[t][2], s[t+w][2]);
            s[t][3] = fminf(s[t][3], s[t+w][3]);
            s[t][4] = fminf(s[t][4], s[t+w][4]);
            s[t][5] = fminf(s[t][5], s[t+w][5]);
        }
        __syncthreads();
    }
    if (t == 0) {
        #pragma unroll
        for (int k = 0; k < 6; ++k) partial[blockIdx.x*6 + k] = s[0][k];
    }
}

__global__ __launch_bounds__(256) void finalize_kernel(
    const float* __restrict__ partial, int nb, float* __restrict__ params)
{
    float mx0=-FLT_MAX, mx1=-FLT_MAX, mx2=-FLT_MAX;
    float mn0= FLT_MAX, mn1= FLT_MAX, mn2= FLT_MAX;
    const int t = threadIdx.x;
    for (int b = t; b < nb; b += blockDim.x) {
        mx0 = fmaxf(mx0, partial[6*b+0]);
        mx1 = fmaxf(mx1, partial[6*b+1]);
        mx2 = fmaxf(mx2, partial[6*b+2]);
        mn0 = fminf(mn0, partial[6*b+3]);
        mn1 = fminf(mn1, partial[6*b+4]);
        mn2 = fminf(mn2, partial[6*b+5]);
    }
    __shared__ float s[256][6];
    s[t][0]=mx0; s[t][1]=mx1; s[t][2]=mx2; s[t][3]=mn0; s[t][4]=mn1; s[t][5]=mn2;
    __syncthreads();
    for (int w = 128; w >= 1; w >>= 1) {
        if (t < w) {
            s[t][0] = fmaxf(s[t][0], s[t+w][0]);
            s[t][1] = fmaxf(s[t][1], s[t+w][1]);
            s[t][2] = fmaxf(s[t][2], s[t+w][2]);
            s[t][3] = fminf(s[t][3], s[t+w][3]);
            s[t][4] = fminf(s[t][4], s[t+w][4]);
            s[t][5] = fminf(s[t][5], s[t+w][5]);
        }
        __syncthreads();
    }
    if (t == 0) {
        float cx = (s[0][0] + s[0][3]) * 0.5f;   // (mmax+mmin)/2, /2 exact
        float cy = (s[0][1] + s[0][4]) * 0.5f;
        float cz = (s[0][2] + s[0][5]) * 0.5f;
        // big = max over flattened centered array == max_c fl(mmax_c - center_c)
        float big = fmaxf(fmaxf(s[0][0] - cx, s[0][1] - cy), s[0][2] - cz);
        params[0] = cx; params[1] = cy; params[2] = cz; params[3] = big;
    }
}

__global__ __launch_bounds__(256) void normalize_kernel(
    const float* __restrict__ iv, const float* __restrict__ vp,
    const float* __restrict__ params, float* __restrict__ out, int n)
{
    const float c0 = params[0], c1 = params[1], c2 = params[2], big = params[3];
    for (int i = blockIdx.x * blockDim.x + threadIdx.x; i < n;
         i += gridDim.x * blockDim.x) {
        int comp = i % 3;
        float c = (comp == 0) ? c0 : ((comp == 1) ? c1 : c2);
        out[i] = ((iv[i] + vp[i]) - c) / big;
    }
}

// ---------------------------------------------------------------------------
extern "C" void kernel_launch(void* const* d_in, const int* in_sizes, int n_in,
                              void* d_out, int out_size, void* d_ws, size_t ws_size,
                              hipStream_t stream) {
    const float* tr  = (const float*)d_in[0];   // translation_p (1,1,F,3)
    const float* q   = (const float*)d_in[1];   // quaternion_p  (1,F,4)
    const float* vp  = (const float*)d_in[2];   // vertices_p    (1,V,3)
    const float* tex = (const float*)d_in[3];   // texture_map   (1,NF,T,T)
    const float* iv  = (const float*)d_in[4];   // ivertices     (1,V,3)
    const float* off = (const float*)d_in[5];   // offsets       (1,1,F,7)
    const int*   of  = (const int*)d_in[6];     // opt_frames    (F,)

    const int F    = in_sizes[6];
    const int nt   = in_sizes[0];   // F*3
    const int nq   = in_sizes[1];   // F*4
    const int nv   = in_sizes[2];   // V*3
    const int ntex = in_sizes[3];
    const int V    = nv / 3;

    float* out    = (float*)d_out;
    float* out_t  = out;
    float* out_q  = out + nt;
    float* out_v  = out + nt + nq;
    float* out_tex= out + nt + nq + nv;
    float* out_td = out + (size_t)nt + nq + nv + ntex;
    float* out_qd = out_td + F;

    float* partial = (float*)d_ws;              // RED_BLOCKS*6 floats
    float* params  = partial + RED_BLOCKS * 6;  // 4 floats

    // Texture pass-through: the only big traffic (268 MB each way).
    hipMemcpyAsync(out_tex, tex, (size_t)ntex * sizeof(float),
                   hipMemcpyDeviceToDevice, stream);

    frames_kernel<<<1, 256, 0, stream>>>(tr, q, off, of,
                                         out_t, out_q, out_td, out_qd, F);
    minmax_kernel<<<RED_BLOCKS, 256, 0, stream>>>(iv, vp, V, partial);
    finalize_kernel<<<1, 256, 0, stream>>>(partial, RED_BLOCKS, params);
    const int nblk = (nv + 255) / 256;
    normalize_kernel<<<nblk, 256, 0, stream>>>(iv, vp, params, out_v, nv);
}

// Round 2
// 109.431 us; speedup vs baseline: 1.0915x; 1.0915x over previous
//
#include <hip/hip_runtime.h>
#include <float.h>
#include <math.h>

#define F_MAX 512
#define RED_BLOCKS 128

typedef float f4 __attribute__((ext_vector_type(4)));

// ---------------------------------------------------------------------------
// Kernel A: per-component min/max over V vertices of (iv+vp)  AND
// (block 0 only) the frame math: quaternion normalize, qmult, t_all,
// gather by opt_frames, tdiff/qdiff.
// ---------------------------------------------------------------------------
__global__ __launch_bounds__(256) void minmax_frames_kernel(
    const float* __restrict__ iv, const float* __restrict__ vp, int V,
    float* __restrict__ partial,
    const float* __restrict__ tr,   // (1,1,F,3)
    const float* __restrict__ q,    // (1,F,4)
    const float* __restrict__ off,  // (1,1,F,7)
    const int*   __restrict__ of,   // (F,)
    float* __restrict__ out_t,      // (F,3)
    float* __restrict__ out_q,      // (F,4)
    float* __restrict__ out_td,     // (F,)
    float* __restrict__ out_qd,     // (F,)
    int F)
{
    const int t = threadIdx.x;

    // ---- min/max partial reduction (all blocks) ----
    float mx0=-FLT_MAX, mx1=-FLT_MAX, mx2=-FLT_MAX;
    float mn0= FLT_MAX, mn1= FLT_MAX, mn2= FLT_MAX;
    for (int v = blockIdx.x * blockDim.x + t; v < V;
         v += gridDim.x * blockDim.x) {
        float a0 = iv[3*v+0] + vp[3*v+0];
        float a1 = iv[3*v+1] + vp[3*v+1];
        float a2 = iv[3*v+2] + vp[3*v+2];
        mx0 = fmaxf(mx0, a0); mn0 = fminf(mn0, a0);
        mx1 = fmaxf(mx1, a1); mn1 = fminf(mn1, a1);
        mx2 = fmaxf(mx2, a2); mn2 = fminf(mn2, a2);
    }
    __shared__ float s[256][6];
    s[t][0]=mx0; s[t][1]=mx1; s[t][2]=mx2; s[t][3]=mn0; s[t][4]=mn1; s[t][5]=mn2;
    __syncthreads();
    for (int w = 128; w >= 1; w >>= 1) {
        if (t < w) {
            s[t][0] = fmaxf(s[t][0], s[t+w][0]);
            s[t][1] = fmaxf(s[t][1], s[t+w][1]);
            s[t][2] = fmaxf(s[t][2], s[t+w][2]);
            s[t][3] = fminf(s[t][3], s[t+w][3]);
            s[t][4] = fminf(s[t][4], s[t+w][4]);
            s[t][5] = fminf(s[t][5], s[t+w][5]);
        }
        __syncthreads();
    }
    if (t == 0) {
        #pragma unroll
        for (int k = 0; k < 6; ++k) partial[blockIdx.x*6 + k] = s[0][k];
    }

    // ---- frame math (block 0 only) ----
    if (blockIdx.x != 0) return;

    __shared__ float qall[F_MAX][4];
    __shared__ float tall[F_MAX][3];

    for (int f = t; f < F; f += blockDim.x) {
        float w1 = q[4*f+0], x1 = q[4*f+1], y1 = q[4*f+2], z1 = q[4*f+3];
        float n1 = sqrtf(w1*w1 + x1*x1 + y1*y1 + z1*z1);
        w1 /= n1; x1 /= n1; y1 /= n1; z1 /= n1;
        float w0 = off[7*f+3], x0 = off[7*f+4], y0 = off[7*f+5], z0 = off[7*f+6];
        float n0 = sqrtf(w0*w0 + x0*x0 + y0*y0 + z0*z0);
        w0 /= n0; x0 /= n0; y0 /= n0; z0 /= n0;
        float pw = -x1*x0 - y1*y0 - z1*z0 + w1*w0;
        float px =  x1*w0 + y1*z0 - z1*y0 + w1*x0;
        float py = -x1*z0 + y1*w0 + z1*x0 + w1*y0;
        float pz =  x1*y0 - y1*x0 + z1*w0 + w1*z0;
        if (f == 0) { pw = w1; px = x1; py = y1; pz = z1; }  // q_all[0] = qn[0]
        qall[f][0] = pw; qall[f][1] = px; qall[f][2] = py; qall[f][3] = pz;
        float o0 = 0.f, o1 = 0.f, o2 = 0.f;
        if (f >= 1) { o0 = off[7*f+0]; o1 = off[7*f+1]; o2 = off[7*f+2]; }
        tall[f][0] = tr[3*f+0] + o0;
        tall[f][1] = tr[3*f+1] + o1;
        tall[f][2] = tr[3*f+2] + o2;
    }
    __syncthreads();

    for (int j = t; j < F; j += blockDim.x) {
        const int fj = of[j];
        out_t[3*j+0] = tall[fj][0];
        out_t[3*j+1] = tall[fj][1];
        out_t[3*j+2] = tall[fj][2];
        out_q[4*j+0] = qall[fj][0];
        out_q[4*j+1] = qall[fj][1];
        out_q[4*j+2] = qall[fj][2];
        out_q[4*j+3] = qall[fj][3];

        float wj = (j == 0) ? 0.0f : (float)(of[j] - of[j-1]);

        float td = 0.0f;
        if (j >= 1) {
            const int fp = of[j-1];
            float ssum = 0.0f;
            #pragma unroll
            for (int c = 0; c < 3; ++c) {
                float d = fabsf(tall[fj][c] - tall[fp][c]);
                if (d < 0.2f) d = 0.0f;
                ssum += d * d;
            }
            td = wj * sqrtf(ssum);
        }
        out_td[j] = td;

        float qd;
        if (j == 0) {
            float sm = qall[F-1][0]*qall[F-1][0] + qall[F-1][1]*qall[F-1][1]
                     + qall[F-1][2]*qall[F-1][2] + qall[F-1][3]*qall[F-1][3];
            qd = wj * (1.0f - sm*sm);   // wj == 0
        } else {
            int ia = fj - 1;
            if (ia < 0) ia += F;        // JAX negative-index wrap
            float sm = qall[ia][0]*qall[fj][0] + qall[ia][1]*qall[fj][1]
                     + qall[ia][2]*qall[fj][2] + qall[ia][3]*qall[fj][3];
            qd = wj * (1.0f - sm*sm);
        }
        out_qd[j] = qd;
    }
}

// ---------------------------------------------------------------------------
// Finalize: reduce block partials -> center[3] + big. 1 block.
// big = max over flattened centered array == max_c fl(mmax_c - center_c)
// (fl(x - c) is monotone in x, so the component max survives centering).
// ---------------------------------------------------------------------------
__global__ __launch_bounds__(256) void finalize_kernel(
    const float* __restrict__ partial, int nb, float* __restrict__ params)
{
    float mx0=-FLT_MAX, mx1=-FLT_MAX, mx2=-FLT_MAX;
    float mn0= FLT_MAX, mn1= FLT_MAX, mn2= FLT_MAX;
    const int t = threadIdx.x;
    for (int b = t; b < nb; b += blockDim.x) {
        mx0 = fmaxf(mx0, partial[6*b+0]);
        mx1 = fmaxf(mx1, partial[6*b+1]);
        mx2 = fmaxf(mx2, partial[6*b+2]);
        mn0 = fminf(mn0, partial[6*b+3]);
        mn1 = fminf(mn1, partial[6*b+4]);
        mn2 = fminf(mn2, partial[6*b+5]);
    }
    __shared__ float s[256][6];
    s[t][0]=mx0; s[t][1]=mx1; s[t][2]=mx2; s[t][3]=mn0; s[t][4]=mn1; s[t][5]=mn2;
    __syncthreads();
    for (int w = 128; w >= 1; w >>= 1) {
        if (t < w) {
            s[t][0] = fmaxf(s[t][0], s[t+w][0]);
            s[t][1] = fmaxf(s[t][1], s[t+w][1]);
            s[t][2] = fmaxf(s[t][2], s[t+w][2]);
            s[t][3] = fminf(s[t][3], s[t+w][3]);
            s[t][4] = fminf(s[t][4], s[t+w][4]);
            s[t][5] = fminf(s[t][5], s[t+w][5]);
        }
        __syncthreads();
    }
    if (t == 0) {
        float cx = (s[0][0] + s[0][3]) * 0.5f;
        float cy = (s[0][1] + s[0][4]) * 0.5f;
        float cz = (s[0][2] + s[0][5]) * 0.5f;
        float big = fmaxf(fmaxf(s[0][0] - cx, s[0][1] - cy), s[0][2] - cz);
        params[0] = cx; params[1] = cy; params[2] = cz; params[3] = big;
    }
}

// ---------------------------------------------------------------------------
// Fused: nontemporal float4 texture copy (the 537 MB traffic) + vertex
// normalize riding in the first grid-stride iteration.
// ---------------------------------------------------------------------------
__global__ __launch_bounds__(256) void copy_norm_kernel(
    const f4* __restrict__ tex, f4* __restrict__ out_tex, long n_tex4,
    const float* __restrict__ iv, const float* __restrict__ vp,
    const float* __restrict__ params, f4* __restrict__ out_v, int nv4)
{
    const long stride = (long)gridDim.x * blockDim.x;
    const long tid0   = (long)blockIdx.x * blockDim.x + threadIdx.x;

    // ---- vertex normalize (first grid-stride pass only touches it) ----
    for (long i = tid0; i < nv4; i += stride) {
        const float c0 = params[0], c1 = params[1], c2 = params[2];
        const float big = params[3];
        f4 a = ((const f4*)iv)[i] + ((const f4*)vp)[i];
        f4 r;
        const int base = (int)(i * 4);
        #pragma unroll
        for (int j = 0; j < 4; ++j) {
            const int comp = (base + j) % 3;
            const float c = (comp == 0) ? c0 : ((comp == 1) ? c1 : c2);
            r[j] = (a[j] - c) / big;
        }
        out_v[i] = r;
    }

    // ---- texture pass-through, nontemporal ----
    for (long i = tid0; i < n_tex4; i += stride) {
        f4 v = __builtin_nontemporal_load(&tex[i]);
        __builtin_nontemporal_store(v, &out_tex[i]);
    }
}

// ---------------------------------------------------------------------------
extern "C" void kernel_launch(void* const* d_in, const int* in_sizes, int n_in,
                              void* d_out, int out_size, void* d_ws, size_t ws_size,
                              hipStream_t stream) {
    const float* tr  = (const float*)d_in[0];   // translation_p (1,1,F,3)
    const float* q   = (const float*)d_in[1];   // quaternion_p  (1,F,4)
    const float* vp  = (const float*)d_in[2];   // vertices_p    (1,V,3)
    const float* tex = (const float*)d_in[3];   // texture_map   (1,NF,T,T)
    const float* iv  = (const float*)d_in[4];   // ivertices     (1,V,3)
    const float* off = (const float*)d_in[5];   // offsets       (1,1,F,7)
    const int*   of  = (const int*)d_in[6];     // opt_frames    (F,)

    const int F    = in_sizes[6];
    const int nt   = in_sizes[0];   // F*3  = 720
    const int nq   = in_sizes[1];   // F*4  = 960
    const int nv   = in_sizes[2];   // V*3  = 300000
    const int ntex = in_sizes[3];   // 67108864
    const int V    = nv / 3;

    float* out     = (float*)d_out;
    float* out_t   = out;
    float* out_q   = out + nt;
    float* out_v   = out + nt + nq;              // offset 1680  (%4==0)
    float* out_tex = out + nt + nq + nv;         // offset 301680 (%4==0)
    float* out_td  = out + (size_t)nt + nq + nv + ntex;
    float* out_qd  = out_td + F;

    float* partial = (float*)d_ws;               // RED_BLOCKS*6 floats
    float* params  = partial + RED_BLOCKS * 6;   // 4 floats

    minmax_frames_kernel<<<RED_BLOCKS, 256, 0, stream>>>(
        iv, vp, V, partial, tr, q, off, of, out_t, out_q, out_td, out_qd, F);
    finalize_kernel<<<1, 256, 0, stream>>>(partial, RED_BLOCKS, params);

    const long n_tex4 = (long)ntex / 4;          // ntex % 4 == 0
    const int  nv4    = nv / 4;                  // nv   % 4 == 0
    copy_norm_kernel<<<2048, 256, 0, stream>>>(
        (const f4*)tex, (f4*)out_tex, n_tex4, iv, vp, params, (f4*)out_v, nv4);
}